// Round 6
// baseline (79.056 us; speedup 1.0000x reference)
//
#include <hip/hip_runtime.h>

#define N_B    4
#define M_PTS  8192
#define K_PTS  8192
#define RPL    8                  // rows per lane
#define BLK_ROWS  (64 * RPL)      // 512 rows per block (4 waves share them)
#define BLK_COLS  (4 * 64)        // 256 columns per block (64 per wave)

// Schraudolph exp2: e = bitcast(int(EXPA - FS*d)), FS = ALPHA*log2(e)*2^23.
// FS folded into a post-sqrt FMA so the distance math runs unscaled (f16-safe).
#define FS    (7.21347520444481703f * 8388608.0f)
#define EXPA  1064879260.0f       // (127 - 0.0565)*2^23, zero-mean rel err
#define LN2   0.69314718055994531f

typedef _Float16 h2 __attribute__((ext_vector_type(2)));

// one-lane whole-wave rotate (DPP wave_ror:1), proven R3-R5
__device__ __forceinline__ float ror1(float x) {
    int i = __float_as_int(x);
    return __int_as_float(__builtin_amdgcn_update_dpp(i, i, 0x13C, 0xF, 0xF, false));
}
__device__ __forceinline__ h2 ror1h(h2 x) {
    int i = *(int*)&x;
    int r = __builtin_amdgcn_update_dpp(i, i, 0x13C, 0xF, 0xF, false);
    return *(h2*)&r;
}

// Single pass; row sums per-lane, column sums via traveling accumulator.
// R5 calibration: pk_f32 = 4 cyc (no throughput gain); f16 pk + v_dot2 ARE
// full-rate per-inst -> distance = 2 insts/pair instead of 4 f32 ops.
// Per pair: pk_sub_f16, fdot2, sqrt(trans), fma(EXPA-FS*d), cvt, rs-add.
__global__ __launch_bounds__(256) void softhaus_pair(
    const float* __restrict__ pred, const float* __restrict__ gt,
    float* __restrict__ row_sum, float* __restrict__ col_sum)
{
    const int n    = blockIdx.z;
    const int rb   = blockIdx.x * BLK_ROWS;
    const int lane = threadIdx.x & 63;
    const int wv   = threadIdx.x >> 6;

    const float2* P = (const float2*)pred + (size_t)n * M_PTS;
    const float2* G = (const float2*)gt   + (size_t)n * K_PTS;

    h2    p[RPL];
    float rs[RPL];
    #pragma unroll
    for (int r = 0; r < RPL; ++r) {
        float2 t = P[rb + r * 64 + lane];
        p[r].x = (_Float16)t.x;
        p[r].y = (_Float16)t.y;
        rs[r] = 0.0f;
    }

    const int c0 = blockIdx.y * BLK_COLS + wv * 64;
    float2 g0 = G[c0 + lane];
    h2 g; g.x = (_Float16)g0.x; g.y = (_Float16)g0.y;
    float cacc = 0.0f;

    #pragma unroll 4
    for (int jj = 0; jj < 64; ++jj) {
        float e[RPL];
        #pragma unroll
        for (int r = 0; r < RPL; ++r) {
            h2 df = p[r] - g;                                    // v_pk_add_f16
            const float s = __builtin_amdgcn_fdot2(df, df, 0.0f, false); // full-rate
            const float v = __builtin_amdgcn_sqrtf(s);           // trans
            const float u = fmaf(v, -FS, EXPA);                  // scale + bias
            e[r] = __int_as_float((int)u);                       // cvt, bits=exp2
            rs[r] += e[r];
        }
        cacc += ((e[0] + e[1]) + (e[2] + e[3])) + ((e[4] + e[5]) + (e[6] + e[7]));
        // rotate gt point + its accumulator one lane; 64 rotations = identity
        g    = ror1h(g);
        cacc = ror1(cacc);
    }

    atomicAdd(&col_sum[(size_t)n * K_PTS + c0 + lane], cacc);   // 16 writers
    #pragma unroll
    for (int r = 0; r < RPL; ++r)                                // 32 writers
        atomicAdd(&row_sum[(size_t)n * M_PTS + rb + r * 64 + lane], rs[r]);
}

// ws: row_sum (N*M) then col_sum (N*K); equal counts -> single 1/(N*M) scale.
__global__ __launch_bounds__(256) void softhaus_finalize(
    const float* __restrict__ sums, float* __restrict__ out)
{
    const int total  = N_B * M_PTS + N_B * K_PTS;
    const int idx    = blockIdx.x * blockDim.x + threadIdx.x;
    const int stride = gridDim.x * blockDim.x;

    float acc = 0.0f;
    for (int i = idx; i < total; i += stride)
        acc -= __builtin_amdgcn_logf(sums[i]) * LN2;   // -log(v)

    #pragma unroll
    for (int off = 32; off > 0; off >>= 1)
        acc += __shfl_down(acc, off);

    __shared__ float wsum[4];
    const int lane = threadIdx.x & 63;
    const int wv   = threadIdx.x >> 6;
    if (lane == 0) wsum[wv] = acc;
    __syncthreads();
    if (threadIdx.x == 0) {
        float b = wsum[0] + wsum[1] + wsum[2] + wsum[3];
        atomicAdd(out, b * (1.0f / (N_B * M_PTS)));
    }
}

extern "C" void kernel_launch(void* const* d_in, const int* in_sizes, int n_in,
                              void* d_out, int out_size, void* d_ws, size_t ws_size,
                              hipStream_t stream) {
    const float* pred = (const float*)d_in[0];
    const float* gt   = (const float*)d_in[1];
    float* ws = (float*)d_ws;

    const size_t acc_bytes = (size_t)(N_B * M_PTS + N_B * K_PTS) * sizeof(float);
    hipMemsetAsync(d_ws, 0, acc_bytes, stream);
    hipMemsetAsync(d_out, 0, sizeof(float), stream);

    dim3 grid(M_PTS / BLK_ROWS, K_PTS / BLK_COLS, N_B);  // 16 x 32 x 4 = 2048
    softhaus_pair<<<grid, 256, 0, stream>>>(pred, gt, ws, ws + (size_t)N_B * M_PTS);
    softhaus_finalize<<<64, 256, 0, stream>>>(ws, (float*)d_out);
}

// Round 7
// 65.910 us; speedup vs baseline: 1.1995x; 1.1995x over previous
//
#include <hip/hip_runtime.h>

#define N_B    4
#define M_PTS  8192
#define K_PTS  8192
#define RPL    8                  // rows per lane (4 packed row-pairs)
#define BLK_ROWS  (64 * RPL)      // 512 rows per block (shared by 4 waves)
#define BLK_COLS  (4 * 64)        // 256 columns per block (64 per wave)

// exp(-ALPHA*d) = exp2(-FS'*d / 2^23) via Schraudolph: e = bitcast(int(EXPA - FS*d))
#define FS    (7.21347520444481703f * 8388608.0f)
#define EXPA  1064879260.0f       // (127 - 0.0565)*2^23, zero-mean rel err (R4+)
#define SQB   0x1FBD1DF5          // bit-trick sqrt magic: d~ = bitcast((bits(s)>>1)+SQB)
#define LN2   0.69314718055994531f

typedef float v2f __attribute__((ext_vector_type(2)));

// one-lane whole-wave rotate (DPP wave_ror:1), proven R3-R5
__device__ __forceinline__ float ror1(float x) {
    int i = __float_as_int(x);
    return __int_as_float(__builtin_amdgcn_update_dpp(i, i, 0x13C, 0xF, 0xF, false));
}

// Single pass; row sums per-lane, column sums via traveling accumulator
// (R1: no DS; R2: no double pass; R5: pk structure = best measured;
//  R6: f16/fdot2 regressed -> reverted). This round: the LAST trans op
// (v_sqrt, ~10 cyc) replaced by shift-add bit sqrt (4 cyc) -> the whole
// inner loop is full-rate VALU: 9 insts (~18 cyc) per pair.
__global__ __launch_bounds__(256) void softhaus_pair(
    const float* __restrict__ pred, const float* __restrict__ gt,
    float* __restrict__ row_sum, float* __restrict__ col_sum)
{
    const int n    = blockIdx.z;
    const int rb   = blockIdx.x * BLK_ROWS;
    const int lane = threadIdx.x & 63;
    const int wv   = threadIdx.x >> 6;

    const float2* P = (const float2*)pred + (size_t)n * M_PTS;
    const float2* G = (const float2*)gt   + (size_t)n * K_PTS;

    v2f px2[RPL / 2], py2[RPL / 2], rs2[RPL / 2];
    #pragma unroll
    for (int i = 0; i < RPL / 2; ++i) {
        float2 a = P[rb + (2 * i    ) * 64 + lane];
        float2 b = P[rb + (2 * i + 1) * 64 + lane];
        px2[i].x = a.x;  px2[i].y = b.x;
        py2[i].x = a.y;  py2[i].y = b.y;
        rs2[i].x = 0.0f; rs2[i].y = 0.0f;
    }

    const int c0 = blockIdx.y * BLK_COLS + wv * 64;
    float2 g0 = G[c0 + lane];
    float gx = g0.x;
    float gy = g0.y;
    float cacc = 0.0f;

    #pragma unroll 4
    for (int jj = 0; jj < 64; ++jj) {
        v2f gxx; gxx.x = gx; gxx.y = gx;
        v2f gyy; gyy.x = gy; gyy.y = gy;
        v2f e2[RPL / 2];
        #pragma unroll
        for (int i = 0; i < RPL / 2; ++i) {
            const v2f dx = px2[i] - gxx;              // pk_add (neg)
            const v2f dy = py2[i] - gyy;              // pk_add
            const v2f s  = dx * dx + dy * dy;         // pk_mul + pk_fma
            // bit sqrt (full-rate int): d~ = bitcast((bits(s)>>1)+SQB)
            const int k0 = (int)(((unsigned)__float_as_int(s.x) >> 1) + SQB);
            const int k1 = (int)(((unsigned)__float_as_int(s.y) >> 1) + SQB);
            // Schraudolph exp2: e = bitcast(int(EXPA - FS*d~))
            const float u0 = fmaf(__int_as_float(k0), -FS, EXPA);
            const float u1 = fmaf(__int_as_float(k1), -FS, EXPA);
            v2f e;
            e.x = __int_as_float((int)u0);
            e.y = __int_as_float((int)u1);
            e2[i] = e;
            rs2[i] += e;                              // pk_add
        }
        const v2f t = (e2[0] + e2[1]) + (e2[2] + e2[3]);  // 3 pk adds
        cacc += t.x + t.y;
        // rotate gt point + its accumulator one lane; 64 rotations = identity
        gx   = ror1(gx);
        gy   = ror1(gy);
        cacc = ror1(cacc);
    }

    atomicAdd(&col_sum[(size_t)n * K_PTS + c0 + lane], cacc);   // 16 writers
    #pragma unroll
    for (int i = 0; i < RPL / 2; ++i) {                          // 32 writers
        atomicAdd(&row_sum[(size_t)n * M_PTS + rb + (2 * i    ) * 64 + lane], rs2[i].x);
        atomicAdd(&row_sum[(size_t)n * M_PTS + rb + (2 * i + 1) * 64 + lane], rs2[i].y);
    }
}

// ws: row_sum (N*M) then col_sum (N*K); equal counts -> single 1/(N*M) scale.
__global__ __launch_bounds__(256) void softhaus_finalize(
    const float* __restrict__ sums, float* __restrict__ out)
{
    const int total  = N_B * M_PTS + N_B * K_PTS;
    const int idx    = blockIdx.x * blockDim.x + threadIdx.x;
    const int stride = gridDim.x * blockDim.x;

    float acc = 0.0f;
    for (int i = idx; i < total; i += stride)
        acc -= __builtin_amdgcn_logf(sums[i]) * LN2;   // -log(v)

    #pragma unroll
    for (int off = 32; off > 0; off >>= 1)
        acc += __shfl_down(acc, off);

    __shared__ float wsum[4];
    const int lane = threadIdx.x & 63;
    const int wv   = threadIdx.x >> 6;
    if (lane == 0) wsum[wv] = acc;
    __syncthreads();
    if (threadIdx.x == 0) {
        float b = wsum[0] + wsum[1] + wsum[2] + wsum[3];
        atomicAdd(out, b * (1.0f / (N_B * M_PTS)));
    }
}

extern "C" void kernel_launch(void* const* d_in, const int* in_sizes, int n_in,
                              void* d_out, int out_size, void* d_ws, size_t ws_size,
                              hipStream_t stream) {
    const float* pred = (const float*)d_in[0];
    const float* gt   = (const float*)d_in[1];
    float* ws = (float*)d_ws;

    const size_t acc_bytes = (size_t)(N_B * M_PTS + N_B * K_PTS) * sizeof(float);
    hipMemsetAsync(d_ws, 0, acc_bytes, stream);
    hipMemsetAsync(d_out, 0, sizeof(float), stream);

    dim3 grid(M_PTS / BLK_ROWS, K_PTS / BLK_COLS, N_B);  // 16 x 32 x 4 = 2048
    softhaus_pair<<<grid, 256, 0, stream>>>(pred, gt, ws, ws + (size_t)N_B * M_PTS);
    softhaus_finalize<<<64, 256, 0, stream>>>(ws, (float*)d_out);
}